// Round 8
// baseline (344.576 us; speedup 1.0000x reference)
//
#include <hip/hip_runtime.h>
#include <hip/hip_bf16.h>
#include <math.h>

// Sizes (fixed by the reference)
#define GG   4096
#define NNODE 64
#define EEDGE 256
#define FFEAT 64
#define DDIM 128
#define EP   32768

// tanh via exp: ~8 VALU instrs vs ~40 for libm tanhf. Numerics validated.
__device__ __forceinline__ float fast_tanh(float x) {
    float e = __expf(2.0f * x);
    return 1.0f - 2.0f / (e + 1.0f);
}

// ---------------------------------------------------------------------------
// Prep (once per call, tiny): Wgf1 = Wg @ Wf1 [64x16] row-major (for k_y),
// bcomb = bg @ Wf1 + bf1 [16], bg32 = 32*bg [128]. Round-8 additions for the
// bilinear-form trick: w1b2[k] = dot(Wl1 row k, bl2), w2b1[m] = dot(Wl2 row
// m, bl1), cconst = dot(bl1, bl2). Also zeroes icnt_g.
// ---------------------------------------------------------------------------
__global__ void k_prep(const float* __restrict__ Wg, const float* __restrict__ Wf1,
                       const float* __restrict__ bf1, const float* __restrict__ bg,
                       const float* __restrict__ Wl1, const float* __restrict__ bl1,
                       const float* __restrict__ Wl2, const float* __restrict__ bl2,
                       float* __restrict__ Wgf1, float* __restrict__ bcomb,
                       float* __restrict__ bg32, int* __restrict__ icnt_g,
                       float* __restrict__ w1b2, float* __restrict__ w2b1,
                       float* __restrict__ cconst) {
    __shared__ float cred[4];
    int t = threadIdx.x;
    for (int o = t; o < 1024; o += 256) {
        int f = o >> 4, j = o & 15;
        float s = 0.f;
        for (int d = 0; d < 128; ++d) s += Wg[f * 128 + d] * Wf1[d * 16 + j];
        Wgf1[o] = s;
    }
    if (t < 16) {
        float s = bf1[t];
        for (int d = 0; d < 128; ++d) s += bg[d] * Wf1[d * 16 + t];
        bcomb[t] = s;
    }
    if (t >= 128) bg32[t - 128] = 32.0f * bg[t - 128];
    for (int i = t; i < 4096; i += 256) icnt_g[i] = 0;
    // w1b2 / w2b1 (one row per thread, contiguous row reads)
    {
        const float* r1 = Wl1 + (size_t)t * 256;
        const float* r2 = Wl2 + (size_t)t * 256;
        float s1 = 0.f, s2 = 0.f;
        for (int j = 0; j < 256; ++j) { s1 += r1[j] * bl2[j]; s2 += r2[j] * bl1[j]; }
        w1b2[t] = s1; w2b1[t] = s2;
    }
    // cconst = dot(bl1, bl2), block-parallel
    {
        float p = bl1[t] * bl2[t];
        for (int o = 32; o; o >>= 1) p += __shfl_down(p, o);
        if ((t & 63) == 0) cred[t >> 6] = p;
        __syncthreads();
        if (t == 0) cconst[0] = cred[0] + cred[1] + cred[2] + cred[3];
    }
}

// ---------------------------------------------------------------------------
// MT[m,k] = dot(Wl2 row m, Wl1 row k)  ==  (Wl2 Wl1^T)[m,k].
// Then U = zc @ MT gives U[d] = M zc[d]^T with M = Wl1 Wl2^T, so
// dot(zc[s], U[d]) = zc[s] M zc[d]^T -- the bilinear term of fx.fy.
// 256 blocks x 256 threads; Wl2 row staged in LDS; Wl1 rows contiguous
// per-thread (L2-resident, 256 KB).
// ---------------------------------------------------------------------------
__global__ __launch_bounds__(256) void k_mt(const float* __restrict__ Wl1,
                                            const float* __restrict__ Wl2,
                                            float* __restrict__ MT) {
    __shared__ __align__(16) float r2[256];
    const int m = blockIdx.x, k = threadIdx.x;
    if (k < 64) *(float4*)&r2[k * 4] = *(const float4*)&Wl2[(size_t)m * 256 + k * 4];
    __syncthreads();
    const float* r1 = Wl1 + (size_t)k * 256;
    float acc = 0.f;
#pragma unroll 8
    for (int j4 = 0; j4 < 64; ++j4) {
        float4 a = *(const float4*)&r1[j4 * 4];
        float4 b = *(const float4*)&r2[j4 * 4];
        acc += a.x * b.x + a.y * b.y + a.z * b.z + a.w * b.w;
    }
    MT[(size_t)m * 256 + k] = acc;
}

// ---------------------------------------------------------------------------
// Y = x @ Wgf1: [262144 x 64] @ [64 x 16]. v2 (confirmed ~-7us vs v1 in the
// R5/R7 A/B): thread (rr,jq,q) owns row-group rr, j-slice jq, k-slice q;
// no redundant HBM reads; W sub-block in registers; shfl_xor reduce over q.
// ---------------------------------------------------------------------------
__global__ __launch_bounds__(256) void k_y(
    const float* __restrict__ x, const float* __restrict__ W,
    float* __restrict__ Y)
{
    const int t = threadIdx.x;
    const int rr = t >> 4, jq = (t >> 2) & 3, q = t & 3;
    float4 w[16];
#pragma unroll
    for (int kk = 0; kk < 16; ++kk)
        w[kk] = *(const float4*)&W[(q * 16 + kk) * 16 + jq * 4];
    const size_t rbase = (size_t)blockIdx.x * 256;
#pragma unroll 2
    for (int it = 0; it < 16; ++it) {
        const int n = it * 16 + rr;
        const float* xr = &x[(rbase + n) * 64 + q * 16];
        float xv[16];
        *(float4*)&xv[0]  = *(const float4*)&xr[0];
        *(float4*)&xv[4]  = *(const float4*)&xr[4];
        *(float4*)&xv[8]  = *(const float4*)&xr[8];
        *(float4*)&xv[12] = *(const float4*)&xr[12];
        float4 acc = {0.f, 0.f, 0.f, 0.f};
#pragma unroll
        for (int kk = 0; kk < 16; ++kk) {
            float a = xv[kk];
            acc.x += a * w[kk].x; acc.y += a * w[kk].y;
            acc.z += a * w[kk].z; acc.w += a * w[kk].w;
        }
        acc.x += __shfl_xor(acc.x, 1); acc.x += __shfl_xor(acc.x, 2);
        acc.y += __shfl_xor(acc.y, 1); acc.y += __shfl_xor(acc.y, 2);
        acc.z += __shfl_xor(acc.z, 1); acc.z += __shfl_xor(acc.z, 2);
        acc.w += __shfl_xor(acc.w, 1); acc.w += __shfl_xor(acc.w, 2);
        if (q == 0)
            *(float4*)&Y[(rbase + n) * 16 + jq * 4] = acc;
    }
}

// ---------------------------------------------------------------------------
// Per-graph kernel v3 (round-5/7 proven 45us). FROZEN this round.
// ---------------------------------------------------------------------------
__global__ __launch_bounds__(256) void k_pg(
    const float* __restrict__ Yg, const int* __restrict__ ei, const float* __restrict__ ew,
    const float* __restrict__ x, const float* __restrict__ bcomb,
    const float* __restrict__ Wf2, const float* __restrict__ bf2,
    float* __restrict__ Qh, float* __restrict__ pens)
{
    __shared__ __align__(16) float sm[2624];
    float* Ys    = sm;                    // 64 x 20; reused as Qh partials (256) in P9
    int*   lsrc  = (int*)(sm + 1280);     // 256 CSR src
    float* lnrm  = sm + 1536;             // 256 CSR norm
    int*   icnt  = (int*)(sm + 1792);     // 64
    int*   offs  = (int*)(sm + 1856);     // 64
    int*   curs  = (int*)(sm + 1920);     // 64
    float* degw  = sm + 1984;             // 64
    float* dinvs = sm + 2048;             // 64
    float* deg2s = sm + 2112;             // 64
    float* dinv2s= sm + 2176;             // 64
    float* cws   = sm + 2240;             // 64 column sums of P
    float* Ss    = sm + 2304;             // 128
    float* LSs   = sm + 2432;             // 128
    float* bcs   = sm + 2560;             // 16
    float* Wf2s  = sm + 2576;             // 32
    float* bf2s  = sm + 2608;             // 2

    const int g = blockIdx.x;
    const int t = threadIdx.x;
    const int n = t >> 2, q = t & 3;

    // P0: stage Y, consts; own edge -> registers; init counters
    int es, ed; float wv;
    {
        const int* eg = ei + (size_t)g * 512;
        es = eg[t];
        ed = eg[256 + t];
        wv = ew[(size_t)g * 256 + t];
        *(float4*)&Ys[n * 20 + q * 4] = *(const float4*)&Yg[(size_t)g * 1024 + t * 4];
        if (t < 16) bcs[t] = bcomb[t];
        if (t < 32) Wf2s[t] = Wf2[t];
        if (t < 2)  bf2s[t] = bf2[t];
        if (t < 64) { icnt[t] = 0; degw[t] = 1.0f; deg2s[t] = 0.0f; }
        if (t < 128) LSs[t] = 0.0f;
    }
    __syncthreads();

    // P1: counts + weighted degrees
    atomicAdd(&icnt[ed], 1);
    atomicAdd(&degw[ed], wv);
    atomicAdd(&deg2s[es], wv);
    __syncthreads();

    // P2: wave0 scans counts -> offsets; dinv; cw init = dinv^2
    if (t < 64) {
        int v = icnt[t], own = v;
        for (int o = 1; o < 64; o <<= 1) { int u = __shfl_up(v, o); if (t >= o) v += u; }
        int excl = v - own;
        offs[t] = excl; curs[t] = excl;
        float dv = rsqrtf(degw[t]);
        dinvs[t] = dv;
        cws[t] = dv * dv;
        float dg = deg2s[t];
        dinv2s[t] = dg > 0.0f ? rsqrtf(fmaxf(dg, 1e-30f)) : 0.0f;
    }
    __syncthreads();

    // P3: place edge into CSR; accumulate cw[src]; laplacian weight in reg
    float lw;
    {
        int pos = atomicAdd(&curs[ed], 1);
        float nm = dinvs[es] * wv * dinvs[ed];
        lsrc[pos] = es;
        lnrm[pos] = nm;
        atomicAdd(&cws[es], nm);
        lw = -dinv2s[es] * wv * dinv2s[ed];
    }
    __syncthreads();

    // P4+P5 fused: 16-wide gather of a1 slice in regs, tanh, logits,
    // 4-lane shfl reduce, softmax at q==0.
    {
        float dv = dinvs[n];
        float sc = dv * dv;
        float4 acc = *(const float4*)&Ys[n * 20 + q * 4];
        acc.x *= sc; acc.y *= sc; acc.z *= sc; acc.w *= sc;
        int o = offs[n], c = icnt[n];
        for (int j = 0; j < c; ++j) {
            int s = lsrc[o + j];
            float nm = lnrm[o + j];
            float4 yv = *(const float4*)&Ys[s * 20 + q * 4];
            acc.x += yv.x * nm; acc.y += yv.y * nm;
            acc.z += yv.z * nm; acc.w += yv.w * nm;
        }
        float4 bc4 = *(const float4*)&bcs[q * 4];
        float t0 = fast_tanh(acc.x + bc4.x);
        float t1 = fast_tanh(acc.y + bc4.y);
        float t2 = fast_tanh(acc.z + bc4.z);
        float t3 = fast_tanh(acc.w + bc4.w);
        float4 wf0 = *(const float4*)&Wf2s[8 * q];
        float4 wf1 = *(const float4*)&Wf2s[8 * q + 4];
        float z0 = t0 * wf0.x + t1 * wf0.z + t2 * wf1.x + t3 * wf1.z;
        float z1 = t0 * wf0.y + t1 * wf0.w + t2 * wf1.y + t3 * wf1.w;
        z0 += __shfl_xor(z0, 1); z0 += __shfl_xor(z0, 2);
        z1 += __shfl_xor(z1, 1); z1 += __shfl_xor(z1, 2);
        if (q == 0) {
            z0 += bf2s[0]; z1 += bf2s[1];
            float m = fmaxf(z0, z1);
            float e0 = __expf(z0 - m), e1 = __expf(z1 - m);
            float inv = 1.0f / (e0 + e1);
            Ss[n * 2] = e0 * inv; Ss[n * 2 + 1] = e1 * inv;
        }
    }
    __syncthreads();

    // P8: LS scatter (own-edge registers; identity added at use)
    {
        float s0 = Ss[ed * 2], s1 = Ss[ed * 2 + 1];
        atomicAdd(&LSs[es * 2],     lw * s0);
        atomicAdd(&LSs[es * 2 + 1], lw * s1);
    }
    __syncthreads();

    // P9: penalty (wave0) + Qh partials (all threads).
    // Qh[g,k] = 0.5 * sum_n cw[n] * x[g,n,k]  (softmax row-sums == 1).
    if (t < 64) {
        float s0 = Ss[t * 2], s1 = Ss[t * 2 + 1];
        float l0 = s0 + LSs[t * 2], l1 = s1 + LSs[t * 2 + 1];
        float p00 = s0 * l0, p01 = s0 * l1, p10 = s1 * l0, p11 = s1 * l1;
        for (int o = 32; o; o >>= 1) {
            p00 += __shfl_down(p00, o); p01 += __shfl_down(p01, o);
            p10 += __shfl_down(p10, o); p11 += __shfl_down(p11, o);
        }
        if (t == 0) {
            float r0 = fmaxf(fabsf(p00) + fabsf(p01), 1e-12f);
            float r1 = fmaxf(fabsf(p10) + fabsf(p11), 1e-12f);
            float d0 = p00 / r0 - 1.0f, d1 = p11 / r1 - 1.0f;
            pens[g] = 0.5f * (d0 * d0 + d1 * d1);
        }
    }
    {
        int k = t & 63, p = t >> 6;
        const float* xg = x + (size_t)g * 4096 + k;
        float qk = 0.f;
#pragma unroll 4
        for (int nn = p * 16; nn < p * 16 + 16; ++nn)
            qk += cws[nn] * xg[(size_t)nn * 64];
        __syncthreads();              // all P4 reads of Ys long done; reuse as partials
        Ys[p * 64 + k] = qk;
    }
    __syncthreads();
    if (t < 64)
        Qh[(size_t)g * 64 + t] = 0.5f * (Ys[t] + Ys[64 + t] + Ys[128 + t] + Ys[192 + t]);
}

// ---------------------------------------------------------------------------
// Parallel CSR build over pos_edges (3 small kernels).
// ---------------------------------------------------------------------------
__global__ void k_cnt(const int* __restrict__ pd, int* __restrict__ icnt) {
    int e = blockIdx.x * 256 + threadIdx.x;
    atomicAdd(&icnt[pd[e]], 1);
}

__global__ void k_scan(const int* __restrict__ icnt, int* __restrict__ offs,
                       int* __restrict__ curs, float* __restrict__ dinv) {
    __shared__ int wsum[4];
    int t = threadIdx.x;
    int base = t * 16;
    int l0,l1,l2,l3,l4,l5,l6,l7,l8,l9,l10,l11,l12,l13,l14,l15;
    l0=icnt[base+0]; l1=icnt[base+1]; l2=icnt[base+2]; l3=icnt[base+3];
    l4=icnt[base+4]; l5=icnt[base+5]; l6=icnt[base+6]; l7=icnt[base+7];
    l8=icnt[base+8]; l9=icnt[base+9]; l10=icnt[base+10]; l11=icnt[base+11];
    l12=icnt[base+12]; l13=icnt[base+13]; l14=icnt[base+14]; l15=icnt[base+15];
    int s = l0+l1+l2+l3+l4+l5+l6+l7+l8+l9+l10+l11+l12+l13+l14+l15;
    int lane = t & 63, w = t >> 6;
    int v = s;
    for (int o = 1; o < 64; o <<= 1) { int u = __shfl_up(v, o); if (lane >= o) v += u; }
    if (lane == 63) wsum[w] = v;
    __syncthreads();
    int woff = 0;
    for (int i = 0; i < 4; ++i) if (i < w) woff += wsum[i];
    int run = woff + v - s;
#define SC(L, I) offs[base+(I)] = run; curs[base+(I)] = run; \
    dinv[base+(I)] = rsqrtf((float)(L) + 1.0f); run += L;
    SC(l0,0) SC(l1,1) SC(l2,2) SC(l3,3) SC(l4,4) SC(l5,5) SC(l6,6) SC(l7,7)
    SC(l8,8) SC(l9,9) SC(l10,10) SC(l11,11) SC(l12,12) SC(l13,13) SC(l14,14) SC(l15,15)
#undef SC
}

__global__ void k_place(const int* __restrict__ pe, const float* __restrict__ dinv,
                        int* __restrict__ curs, int* __restrict__ csr_src,
                        float* __restrict__ csr_nrm) {
    int e = blockIdx.x * 256 + threadIdx.x;
    int s = pe[e], d = pe[EP + e];
    int pos = atomicAdd(&curs[d], 1);
    csr_src[pos] = s;
    csr_nrm[pos] = dinv[s] * dinv[d];
}

// ---------------------------------------------------------------------------
// CSR gathers: out[g] = in[g]*dinv[g]^2 + sum_{edges->g} in[src]*nrm.
// ---------------------------------------------------------------------------
__global__ void k_gather128(const int* __restrict__ offs, const int* __restrict__ icnt,
                            const int* __restrict__ csr_src, const float* __restrict__ csr_nrm,
                            const float* __restrict__ dinv, const float* __restrict__ in,
                            float* __restrict__ out) {
    int g = blockIdx.x, d = threadIdx.x;  // 128 threads
    float dv = dinv[g];
    float acc = in[(size_t)g * 128 + d] * dv * dv;
    int o = offs[g], c = icnt[g];
    for (int j = 0; j < c; ++j)
        acc += in[(size_t)csr_src[o + j] * 128 + d] * csr_nrm[o + j];
    out[(size_t)g * 128 + d] = acc;
}

__global__ void k_gather256(const int* __restrict__ offs, const int* __restrict__ icnt,
                            const int* __restrict__ csr_src, const float* __restrict__ csr_nrm,
                            const float* __restrict__ dinv, const float* __restrict__ in,
                            float* __restrict__ out) {
    int g = blockIdx.x, d = threadIdx.x;  // 256 threads
    float dv = dinv[g];
    float acc = in[(size_t)g * 256 + d] * dv * dv;
    int o = offs[g], c = icnt[g];
    for (int j = 0; j < c; ++j)
        acc += in[(size_t)csr_src[o + j] * 256 + d] * csr_nrm[o + j];
    out[(size_t)g * 256 + d] = acc;
}

// ---------------------------------------------------------------------------
// Double-buffered tiled fp32 GEMM (unchanged): 64x64 tile, 256 threads,
// 4x4 microtile, BK=32, register-prefetch + 2x LDS buffers.
// Dual-output option: blockIdx.y >= gridDim.y/2 uses B1/bias1/C1 (shared A).
// ---------------------------------------------------------------------------
__global__ __launch_bounds__(256) void k_gemm(
    const float* __restrict__ A,
    const float* __restrict__ B0, const float* __restrict__ bias0, float* __restrict__ C0,
    const float* __restrict__ B1, const float* __restrict__ bias1, float* __restrict__ C1,
    int M, int K, int N, int dorelu)
{
    __shared__ __align__(16) float lds[2 * 4352];
    const float* B = B0; const float* bias = bias0; float* C = C0;
    int by = blockIdx.y;
    if (B1 != nullptr && by >= (int)(gridDim.y >> 1)) {
        B = B1; bias = bias1; C = C1; by -= (gridDim.y >> 1);
    }
    const int mb = blockIdx.x * 64, nbb = by * 64;
    const int t = threadIdx.x;
    const int tm4 = (t >> 4) * 4, tn4 = (t & 15) * 4;
    const int ma = t >> 2, ka = (t & 3) * 8;
    const int kb = t >> 3, nb8 = (t & 7) * 8;

    float4 pa0, pa1, pb0, pb1;
#define LOADT(K0) { \
    const float* Ap = &A[(size_t)(mb + ma) * K + (K0) + ka]; \
    pa0 = *(const float4*)Ap; pa1 = *(const float4*)(Ap + 4); \
    const float* Bp = &B[(size_t)((K0) + kb) * N + nbb + nb8]; \
    pb0 = *(const float4*)Bp; pb1 = *(const float4*)(Bp + 4); }
#define STORET(BUF) { \
    float* At_ = lds + (BUF) * 4352; \
    At_[(ka + 0) * 68 + ma] = pa0.x; At_[(ka + 1) * 68 + ma] = pa0.y; \
    At_[(ka + 2) * 68 + ma] = pa0.z; At_[(ka + 3) * 68 + ma] = pa0.w; \
    At_[(ka + 4) * 68 + ma] = pa1.x; At_[(ka + 5) * 68 + ma] = pa1.y; \
    At_[(ka + 6) * 68 + ma] = pa1.z; At_[(ka + 7) * 68 + ma] = pa1.w; \
    float* Bs_ = lds + (BUF) * 4352 + 2176; \
    *(float4*)&Bs_[kb * 68 + nb8] = pb0; *(float4*)&Bs_[kb * 68 + nb8 + 4] = pb1; }

    float4 ca0 = {0,0,0,0}, ca1 = {0,0,0,0}, ca2 = {0,0,0,0}, ca3 = {0,0,0,0};
    const int nk0 = K >> 5;
    LOADT(0)
    STORET(0)
    __syncthreads();
    for (int it = 0; it < nk0; ++it) {
        if (it + 1 < nk0) LOADT((it + 1) * 32)
        const float* At_ = lds + (it & 1) * 4352;
        const float* Bs_ = At_ + 2176;
#pragma unroll
        for (int k = 0; k < 32; ++k) {
            float4 av = *(const float4*)&At_[k * 68 + tm4];
            float4 bv = *(const float4*)&Bs_[k * 68 + tn4];
            ca0.x += av.x * bv.x; ca0.y += av.x * bv.y; ca0.z += av.x * bv.z; ca0.w += av.x * bv.w;
            ca1.x += av.y * bv.x; ca1.y += av.y * bv.y; ca1.z += av.y * bv.z; ca1.w += av.y * bv.w;
            ca2.x += av.z * bv.x; ca2.y += av.z * bv.y; ca2.z += av.z * bv.z; ca2.w += av.z * bv.w;
            ca3.x += av.w * bv.x; ca3.y += av.w * bv.y; ca3.z += av.w * bv.z; ca3.w += av.w * bv.w;
        }
        if (it + 1 < nk0) {
            STORET((it + 1) & 1)
            __syncthreads();
        }
    }
#undef LOADT
#undef STORET
    float4 bv4 = {0, 0, 0, 0};
    if (bias) bv4 = *(const float4*)&bias[nbb + tn4];
#define CST(I, CV) { \
    float4 v; v.x = CV.x + bv4.x; v.y = CV.y + bv4.y; v.z = CV.z + bv4.z; v.w = CV.w + bv4.w; \
    if (dorelu) { v.x = fmaxf(v.x, 0.f); v.y = fmaxf(v.y, 0.f); v.z = fmaxf(v.z, 0.f); v.w = fmaxf(v.w, 0.f); } \
    *(float4*)&C[(size_t)(mb + tm4 + (I)) * N + nbb + tn4] = v; }
    CST(0, ca0) CST(1, ca1) CST(2, ca2) CST(3, ca3)
#undef CST
}

// z = mu + eps*exp(min(ls,10)); zc = [emb, z]; per-graph KL partial.
// Round-8: also a[g] = dot(zc[g], w1b2), b[g] = dot(zc[g], w2b1) for the
// bilinear-form pred (folds the bias terms of fx.fy).
__global__ void k_fin_z(const float* __restrict__ mu_arr, const float* __restrict__ ls_arr,
                        const float* __restrict__ eps, const float* __restrict__ emb,
                        const float* __restrict__ w1b2, const float* __restrict__ w2b1,
                        float* __restrict__ zc, float* __restrict__ klp,
                        float* __restrict__ a_arr, float* __restrict__ b_arr) {
    __shared__ float smw[6];
    int g = blockIdx.x, d = threadIdx.x;  // 128 threads
    int idx = g * 128 + d;
    float mu = mu_arr[idx];
    float ls = fminf(ls_arr[idx], 10.0f);
    float e  = __expf(ls);
    float z = mu + eps[idx] * e;
    float em = emb[idx];
    zc[(size_t)g * 256 + d] = em;
    zc[(size_t)g * 256 + 128 + d] = z;
    float term = 1.0f + 2.0f * ls - mu * mu - e * e;
    float av = em * w1b2[d] + z * w1b2[128 + d];
    float bv = em * w2b1[d] + z * w2b1[128 + d];
    for (int o = 32; o; o >>= 1) {
        term += __shfl_down(term, o);
        av   += __shfl_down(av, o);
        bv   += __shfl_down(bv, o);
    }
    if ((d & 63) == 0) { int w = d >> 6; smw[w] = term; smw[2 + w] = av; smw[4 + w] = bv; }
    __syncthreads();
    if (d == 0) {
        klp[g]   = smw[0] + smw[1];
        a_arr[g] = smw[2] + smw[3];
        b_arr[g] = smw[4] + smw[5];
    }
}

// Edge predictions via bilinear form: sigmoid(dot(zc[s], U[d]) + a[s] +
// b[d] + c). 16 lanes per edge; per-block log partial (16 edges).
__global__ void k_pred(const float* __restrict__ ZC, const float* __restrict__ U,
                       const float* __restrict__ a_arr, const float* __restrict__ b_arr,
                       const float* __restrict__ cconst,
                       const int* __restrict__ pos, const int* __restrict__ neg,
                       float* __restrict__ out, float* __restrict__ predp) {
    __shared__ float smw[16];
    int t = threadIdx.x, sub = t >> 4, l = t & 15;
    int eg = blockIdx.x * 16 + sub;
    int isneg = eg >= EP;
    int e = eg - (isneg ? EP : 0);
    const int* eix = isneg ? neg : pos;
    int s = eix[e], d = eix[EP + e];
    const float4* Ar = (const float4*)(ZC + (size_t)s * 256);
    const float4* Br = (const float4*)(U + (size_t)d * 256);
    float dot = 0.f;
#pragma unroll
    for (int q = 0; q < 4; ++q) {
        float4 av = Ar[l + 16 * q], bv = Br[l + 16 * q];
        dot += av.x * bv.x + av.y * bv.y + av.z * bv.z + av.w * bv.w;
    }
    for (int o = 8; o; o >>= 1) dot += __shfl_down(dot, o);
    if (l == 0) {
        dot += a_arr[s] + b_arr[d] + cconst[0];
        float p = 1.0f / (1.0f + __expf(-dot));
        float term;
        if (isneg) { out[2 + EP + e] = p; term = __logf(1.0f - p + 1e-15f); }
        else       { out[2 + e] = p;      term = __logf(p + 1e-15f); }
        smw[sub] = term;
    }
    __syncthreads();
    if (t == 0) {
        float s16 = 0.f;
#pragma unroll
        for (int i = 0; i < 16; ++i) s16 += smw[i];
        predp[blockIdx.x] = s16;
    }
}

// Final scalar reductions (predp: 2048 pos + 2048 neg)
__global__ void k_final(const float* __restrict__ pens, const float* __restrict__ klp,
                        const float* __restrict__ predp, float* __restrict__ out) {
    __shared__ float sm[16];
    int t = threadIdx.x;
    float s_pen = 0.f, s_kl = 0.f, s_pos = 0.f, s_neg = 0.f;
    for (int i = t; i < 4096; i += 256) { s_pen += pens[i]; s_kl += klp[i]; }
    for (int i = t; i < 2048; i += 256) { s_pos += predp[i]; s_neg += predp[2048 + i]; }
    for (int o = 32; o; o >>= 1) {
        s_pen += __shfl_down(s_pen, o); s_kl += __shfl_down(s_kl, o);
        s_pos += __shfl_down(s_pos, o); s_neg += __shfl_down(s_neg, o);
    }
    int w = t >> 6;
    if ((t & 63) == 0) { sm[w] = s_pen; sm[4 + w] = s_kl; sm[8 + w] = s_pos; sm[12 + w] = s_neg; }
    __syncthreads();
    if (t == 0) {
        float pen = sm[0] + sm[1] + sm[2] + sm[3];
        float kls = sm[4] + sm[5] + sm[6] + sm[7];
        float pos = sm[8] + sm[9] + sm[10] + sm[11];
        float neg = sm[12] + sm[13] + sm[14] + sm[15];
        float rec = -(pos / 32768.0f) - (neg / 32768.0f);
        out[0] = rec - 0.5f * kls / (4096.0f * 4096.0f);
        out[1] = pen * (1.0f / 4096.0f);
    }
}

extern "C" void kernel_launch(void* const* d_in, const int* in_sizes, int n_in,
                              void* d_out, int out_size, void* d_ws, size_t ws_size,
                              hipStream_t stream) {
    const float* x   = (const float*)d_in[0];
    const int*   ei  = (const int*)d_in[1];
    const float* ew  = (const float*)d_in[2];
    const int*   pos = (const int*)d_in[3];
    const int*   neg = (const int*)d_in[4];
    const float* eps = (const float*)d_in[5];
    const float* Wg  = (const float*)d_in[6];
    const float* bg  = (const float*)d_in[7];
    const float* Wf1 = (const float*)d_in[8];
    const float* bf1 = (const float*)d_in[9];
    const float* Wf2 = (const float*)d_in[10];
    const float* bf2 = (const float*)d_in[11];
    const float* Wc1 = (const float*)d_in[12];
    const float* bc1 = (const float*)d_in[13];
    const float* Wmu = (const float*)d_in[14];
    const float* bmu = (const float*)d_in[15];
    const float* Wls = (const float*)d_in[16];
    const float* bls = (const float*)d_in[17];
    const float* emb = (const float*)d_in[18];
    const float* Wl1 = (const float*)d_in[19];
    const float* bl1 = (const float*)d_in[20];
    const float* Wl2 = (const float*)d_in[21];
    const float* bl2 = (const float*)d_in[22];
    float* out = (float*)d_out;
    float* ws  = (float*)d_ws;

    // Workspace layout (floats), footprint unchanged (~30.84 MB)
    float* g_embs  = ws + 0;         // 524288
    float* dinv    = ws + 524288;    // 4096
    int*   icnt_g  = (int*)(ws + 528384);  // 4096
    int*   off_g   = (int*)(ws + 532480);  // 4096
    int*   cur_g   = (int*)(ws + 536576);  // 4096
    int*   csr_src = (int*)(ws + 540672);  // 32768
    float* csr_nrm = ws + 573440;    // 32768
    float* Qh      = ws + 606208;    // 262144
    float* ga      = ws + 868352;    // 524288
    float* h       = ws + 1392640;   // 1048576
    float* ha      = ws + 2441216;   // 1048576
    float* mu_arr  = ws + 3489792;   // 524288
    float* ls_arr  = ws + 4014080;   // 524288
    float* zc      = ws + 4538368;   // 1048576
    float* Ubuf    = ws + 5586944;   // 1048576 (was Abuf; only 1/4 used now)
    float* MT      = ws + 6635520;   // 65536 (in old Bbuf region)
    float* w1b2    = ws + 6701056;   // 256
    float* w2b1    = ws + 6701312;   // 256
    float* cconst  = ws + 6701568;   // 1
    float* pens    = ws + 7684096;   // 4096
    float* klp     = ws + 7688192;   // 4096
    float* predp   = ws + 7692288;   // 4096
    float* a_arr   = ws + 7696384;   // 4096
    float* b_arr   = ws + 7700480;   // 4096
    float* Wgf1    = ws + 7708672;   // 1024
    float* bcomb   = ws + 7709696;   // 16
    float* bg32    = ws + 7709712;   // 128
    // Y (262144 x 16 = 4,194,304 floats) overlaps h..zc exactly:
    // [1392640, 5586944). All of h/ha/mu/ls/zc are written only AFTER k_pg
    // has consumed Y (in-stream order), so this adds no workspace.
    float* Y       = ws + 1392640;

    // Prep (also zeroes icnt_g; now also w1b2/w2b1/cconst), MT = Wl2 Wl1^T,
    // Y precompute, per-graph stage
    k_prep<<<1, 256, 0, stream>>>(Wg, Wf1, bf1, bg, Wl1, bl1, Wl2, bl2,
                                  Wgf1, bcomb, bg32, icnt_g, w1b2, w2b1, cconst);
    k_mt<<<256, 256, 0, stream>>>(Wl1, Wl2, MT);
    k_y<<<1024, 256, 0, stream>>>(x, Wgf1, Y);
    k_pg<<<GG, 256, 0, stream>>>(Y, ei, ew, x, bcomb, Wf2, bf2, Qh, pens);
    // g_embs = Qh @ Wg + 32*bg
    k_gemm<<<dim3(64, 2), 256, 0, stream>>>(Qh, Wg, bg32, g_embs,
                                            nullptr, nullptr, nullptr, GG, 64, 128, 0);

    // Parallel CSR build over pos_edges
    k_cnt<<<EP / 256, 256, 0, stream>>>(pos + EP, icnt_g);
    k_scan<<<1, 256, 0, stream>>>(icnt_g, off_g, cur_g, dinv);
    k_place<<<EP / 256, 256, 0, stream>>>(pos, dinv, cur_g, csr_src, csr_nrm);

    // h = relu((A g_embs) @ Wc1 + bc1)
    k_gather128<<<GG, 128, 0, stream>>>(off_g, icnt_g, csr_src, csr_nrm, dinv, g_embs, ga);
    k_gemm<<<dim3(64, 4), 256, 0, stream>>>(ga, Wc1, bc1, h,
                                            nullptr, nullptr, nullptr, GG, 128, 256, 1);

    // mu/ls = (A h) @ {Wmu,Wls} + {bmu,bls}
    k_gather256<<<GG, 256, 0, stream>>>(off_g, icnt_g, csr_src, csr_nrm, dinv, h, ha);
    k_gemm<<<dim3(64, 4), 256, 0, stream>>>(ha, Wmu, bmu, mu_arr,
                                            Wls, bls, ls_arr, GG, 256, 128, 0);
    k_fin_z<<<GG, 128, 0, stream>>>(mu_arr, ls_arr, eps, emb, w1b2, w2b1,
                                    zc, klp, a_arr, b_arr);

    // U = zc @ MT  (replaces the dual gemm4: one product instead of two)
    k_gemm<<<dim3(64, 4), 256, 0, stream>>>(zc, MT, nullptr, Ubuf,
                                            nullptr, nullptr, nullptr, GG, 256, 256, 0);

    // Edge predictions + scalars (16 edges/block)
    k_pred<<<(2 * EP) / 16, 256, 0, stream>>>(zc, Ubuf, a_arr, b_arr, cconst,
                                              pos, neg, out, predp);
    k_final<<<1, 256, 0, stream>>>(pens, klp, predp, out);
}

// Round 9
// 326.167 us; speedup vs baseline: 1.0564x; 1.0564x over previous
//
#include <hip/hip_runtime.h>
#include <hip/hip_bf16.h>
#include <math.h>

// Sizes (fixed by the reference)
#define GG   4096
#define NNODE 64
#define EEDGE 256
#define FFEAT 64
#define DDIM 128
#define EP   32768

// tanh via exp: ~8 VALU instrs vs ~40 for libm tanhf. Numerics validated.
__device__ __forceinline__ float fast_tanh(float x) {
    float e = __expf(2.0f * x);
    return 1.0f - 2.0f / (e + 1.0f);
}

// ---------------------------------------------------------------------------
// Prep (once per call, tiny): Wgf1 = Wg @ Wf1 [64x16] row-major (for k_y),
// bcomb = bg @ Wf1 + bf1 [16], bg32 = 32*bg [128]. Also zeroes icnt_g.
// R9: REVERTED to R7 form -- the R8 w1b2/w2b1 row-dots here were a
// single-block serial head (~+20us); they moved to k_mt (parallel).
// ---------------------------------------------------------------------------
__global__ void k_prep(const float* __restrict__ Wg, const float* __restrict__ Wf1,
                       const float* __restrict__ bf1, const float* __restrict__ bg,
                       float* __restrict__ Wgf1, float* __restrict__ bcomb,
                       float* __restrict__ bg32, int* __restrict__ icnt_g) {
    int t = threadIdx.x;
    for (int o = t; o < 1024; o += 256) {
        int f = o >> 4, j = o & 15;
        float s = 0.f;
        for (int d = 0; d < 128; ++d) s += Wg[f * 128 + d] * Wf1[d * 16 + j];
        Wgf1[o] = s;
    }
    if (t < 16) {
        float s = bf1[t];
        for (int d = 0; d < 128; ++d) s += bg[d] * Wf1[d * 16 + t];
        bcomb[t] = s;
    }
    if (t >= 128) bg32[t - 128] = 32.0f * bg[t - 128];
    for (int i = t; i < 4096; i += 256) icnt_g[i] = 0;
}

// ---------------------------------------------------------------------------
// MT[m,k] = dot(Wl2 row m, Wl1 row k) == (Wl2 Wl1^T)[m,k]; 256 blocks.
// R9: also produces (in parallel, piggybacked on rows already streaming):
//   w2b1[m] = dot(Wl2 row m, bl1)   -- block reduction over the staged row
//   w1b2[k] = dot(Wl1 row k, bl2)   -- block 0 only, fused into the MAC loop
//   cconst  = dot(bl1, bl2)         -- block 0 reduction
// ---------------------------------------------------------------------------
__global__ __launch_bounds__(256) void k_mt(const float* __restrict__ Wl1,
                                            const float* __restrict__ Wl2,
                                            const float* __restrict__ bl1,
                                            const float* __restrict__ bl2,
                                            float* __restrict__ MT,
                                            float* __restrict__ w1b2,
                                            float* __restrict__ w2b1,
                                            float* __restrict__ cconst) {
    __shared__ __align__(16) float r2[256];
    __shared__ __align__(16) float bl2s[256];
    __shared__ float red[4];
    const int m = blockIdx.x, k = threadIdx.x;
    if (k < 64) *(float4*)&r2[k * 4] = *(const float4*)&Wl2[(size_t)m * 256 + k * 4];
    if (m == 0) bl2s[k] = bl2[k];
    __syncthreads();
    const float* r1 = Wl1 + (size_t)k * 256;
    float acc = 0.f;
    if (m == 0) {
        float accb = 0.f;
#pragma unroll 8
        for (int j4 = 0; j4 < 64; ++j4) {
            float4 a = *(const float4*)&r1[j4 * 4];
            float4 b = *(const float4*)&r2[j4 * 4];
            float4 c = *(const float4*)&bl2s[j4 * 4];
            acc  += a.x * b.x + a.y * b.y + a.z * b.z + a.w * b.w;
            accb += a.x * c.x + a.y * c.y + a.z * c.z + a.w * c.w;
        }
        w1b2[k] = accb;
    } else {
#pragma unroll 8
        for (int j4 = 0; j4 < 64; ++j4) {
            float4 a = *(const float4*)&r1[j4 * 4];
            float4 b = *(const float4*)&r2[j4 * 4];
            acc += a.x * b.x + a.y * b.y + a.z * b.z + a.w * b.w;
        }
    }
    MT[(size_t)m * 256 + k] = acc;
    // w2b1[m] = dot(r2, bl1)
    {
        float p = r2[k] * bl1[k];
        for (int o = 32; o; o >>= 1) p += __shfl_down(p, o);
        if ((k & 63) == 0) red[k >> 6] = p;
        __syncthreads();
        if (k == 0) w2b1[m] = red[0] + red[1] + red[2] + red[3];
    }
    // cconst (block 0 only; barrier before reusing red)
    if (m == 0) {
        __syncthreads();
        float p = bl1[k] * bl2s[k];
        for (int o = 32; o; o >>= 1) p += __shfl_down(p, o);
        if ((k & 63) == 0) red[k >> 6] = p;
        __syncthreads();
        if (k == 0) cconst[0] = red[0] + red[1] + red[2] + red[3];
    }
}

// ---------------------------------------------------------------------------
// Y = x @ Wgf1: [262144 x 64] @ [64 x 16]. v2 (confirmed ~-7us vs v1 in the
// R5/R7 A/B): thread (rr,jq,q) owns row-group rr, j-slice jq, k-slice q;
// no redundant HBM reads; W sub-block in registers; shfl_xor reduce over q.
// ---------------------------------------------------------------------------
__global__ __launch_bounds__(256) void k_y(
    const float* __restrict__ x, const float* __restrict__ W,
    float* __restrict__ Y)
{
    const int t = threadIdx.x;
    const int rr = t >> 4, jq = (t >> 2) & 3, q = t & 3;
    float4 w[16];
#pragma unroll
    for (int kk = 0; kk < 16; ++kk)
        w[kk] = *(const float4*)&W[(q * 16 + kk) * 16 + jq * 4];
    const size_t rbase = (size_t)blockIdx.x * 256;
#pragma unroll 2
    for (int it = 0; it < 16; ++it) {
        const int n = it * 16 + rr;
        const float* xr = &x[(rbase + n) * 64 + q * 16];
        float xv[16];
        *(float4*)&xv[0]  = *(const float4*)&xr[0];
        *(float4*)&xv[4]  = *(const float4*)&xr[4];
        *(float4*)&xv[8]  = *(const float4*)&xr[8];
        *(float4*)&xv[12] = *(const float4*)&xr[12];
        float4 acc = {0.f, 0.f, 0.f, 0.f};
#pragma unroll
        for (int kk = 0; kk < 16; ++kk) {
            float a = xv[kk];
            acc.x += a * w[kk].x; acc.y += a * w[kk].y;
            acc.z += a * w[kk].z; acc.w += a * w[kk].w;
        }
        acc.x += __shfl_xor(acc.x, 1); acc.x += __shfl_xor(acc.x, 2);
        acc.y += __shfl_xor(acc.y, 1); acc.y += __shfl_xor(acc.y, 2);
        acc.z += __shfl_xor(acc.z, 1); acc.z += __shfl_xor(acc.z, 2);
        acc.w += __shfl_xor(acc.w, 1); acc.w += __shfl_xor(acc.w, 2);
        if (q == 0)
            *(float4*)&Y[(rbase + n) * 16 + jq * 4] = acc;
    }
}

// ---------------------------------------------------------------------------
// Per-graph kernel v3 (round-5/7/8 proven 45us). FROZEN.
// ---------------------------------------------------------------------------
__global__ __launch_bounds__(256) void k_pg(
    const float* __restrict__ Yg, const int* __restrict__ ei, const float* __restrict__ ew,
    const float* __restrict__ x, const float* __restrict__ bcomb,
    const float* __restrict__ Wf2, const float* __restrict__ bf2,
    float* __restrict__ Qh, float* __restrict__ pens)
{
    __shared__ __align__(16) float sm[2624];
    float* Ys    = sm;                    // 64 x 20; reused as Qh partials (256) in P9
    int*   lsrc  = (int*)(sm + 1280);     // 256 CSR src
    float* lnrm  = sm + 1536;             // 256 CSR norm
    int*   icnt  = (int*)(sm + 1792);     // 64
    int*   offs  = (int*)(sm + 1856);     // 64
    int*   curs  = (int*)(sm + 1920);     // 64
    float* degw  = sm + 1984;             // 64
    float* dinvs = sm + 2048;             // 64
    float* deg2s = sm + 2112;             // 64
    float* dinv2s= sm + 2176;             // 64
    float* cws   = sm + 2240;             // 64 column sums of P
    float* Ss    = sm + 2304;             // 128
    float* LSs   = sm + 2432;             // 128
    float* bcs   = sm + 2560;             // 16
    float* Wf2s  = sm + 2576;             // 32
    float* bf2s  = sm + 2608;             // 2

    const int g = blockIdx.x;
    const int t = threadIdx.x;
    const int n = t >> 2, q = t & 3;

    // P0: stage Y, consts; own edge -> registers; init counters
    int es, ed; float wv;
    {
        const int* eg = ei + (size_t)g * 512;
        es = eg[t];
        ed = eg[256 + t];
        wv = ew[(size_t)g * 256 + t];
        *(float4*)&Ys[n * 20 + q * 4] = *(const float4*)&Yg[(size_t)g * 1024 + t * 4];
        if (t < 16) bcs[t] = bcomb[t];
        if (t < 32) Wf2s[t] = Wf2[t];
        if (t < 2)  bf2s[t] = bf2[t];
        if (t < 64) { icnt[t] = 0; degw[t] = 1.0f; deg2s[t] = 0.0f; }
        if (t < 128) LSs[t] = 0.0f;
    }
    __syncthreads();

    // P1: counts + weighted degrees
    atomicAdd(&icnt[ed], 1);
    atomicAdd(&degw[ed], wv);
    atomicAdd(&deg2s[es], wv);
    __syncthreads();

    // P2: wave0 scans counts -> offsets; dinv; cw init = dinv^2
    if (t < 64) {
        int v = icnt[t], own = v;
        for (int o = 1; o < 64; o <<= 1) { int u = __shfl_up(v, o); if (t >= o) v += u; }
        int excl = v - own;
        offs[t] = excl; curs[t] = excl;
        float dv = rsqrtf(degw[t]);
        dinvs[t] = dv;
        cws[t] = dv * dv;
        float dg = deg2s[t];
        dinv2s[t] = dg > 0.0f ? rsqrtf(fmaxf(dg, 1e-30f)) : 0.0f;
    }
    __syncthreads();

    // P3: place edge into CSR; accumulate cw[src]; laplacian weight in reg
    float lw;
    {
        int pos = atomicAdd(&curs[ed], 1);
        float nm = dinvs[es] * wv * dinvs[ed];
        lsrc[pos] = es;
        lnrm[pos] = nm;
        atomicAdd(&cws[es], nm);
        lw = -dinv2s[es] * wv * dinv2s[ed];
    }
    __syncthreads();

    // P4+P5 fused: 16-wide gather of a1 slice in regs, tanh, logits,
    // 4-lane shfl reduce, softmax at q==0.
    {
        float dv = dinvs[n];
        float sc = dv * dv;
        float4 acc = *(const float4*)&Ys[n * 20 + q * 4];
        acc.x *= sc; acc.y *= sc; acc.z *= sc; acc.w *= sc;
        int o = offs[n], c = icnt[n];
        for (int j = 0; j < c; ++j) {
            int s = lsrc[o + j];
            float nm = lnrm[o + j];
            float4 yv = *(const float4*)&Ys[s * 20 + q * 4];
            acc.x += yv.x * nm; acc.y += yv.y * nm;
            acc.z += yv.z * nm; acc.w += yv.w * nm;
        }
        float4 bc4 = *(const float4*)&bcs[q * 4];
        float t0 = fast_tanh(acc.x + bc4.x);
        float t1 = fast_tanh(acc.y + bc4.y);
        float t2 = fast_tanh(acc.z + bc4.z);
        float t3 = fast_tanh(acc.w + bc4.w);
        float4 wf0 = *(const float4*)&Wf2s[8 * q];
        float4 wf1 = *(const float4*)&Wf2s[8 * q + 4];
        float z0 = t0 * wf0.x + t1 * wf0.z + t2 * wf1.x + t3 * wf1.z;
        float z1 = t0 * wf0.y + t1 * wf0.w + t2 * wf1.y + t3 * wf1.w;
        z0 += __shfl_xor(z0, 1); z0 += __shfl_xor(z0, 2);
        z1 += __shfl_xor(z1, 1); z1 += __shfl_xor(z1, 2);
        if (q == 0) {
            z0 += bf2s[0]; z1 += bf2s[1];
            float m = fmaxf(z0, z1);
            float e0 = __expf(z0 - m), e1 = __expf(z1 - m);
            float inv = 1.0f / (e0 + e1);
            Ss[n * 2] = e0 * inv; Ss[n * 2 + 1] = e1 * inv;
        }
    }
    __syncthreads();

    // P8: LS scatter (own-edge registers; identity added at use)
    {
        float s0 = Ss[ed * 2], s1 = Ss[ed * 2 + 1];
        atomicAdd(&LSs[es * 2],     lw * s0);
        atomicAdd(&LSs[es * 2 + 1], lw * s1);
    }
    __syncthreads();

    // P9: penalty (wave0) + Qh partials (all threads).
    // Qh[g,k] = 0.5 * sum_n cw[n] * x[g,n,k]  (softmax row-sums == 1).
    if (t < 64) {
        float s0 = Ss[t * 2], s1 = Ss[t * 2 + 1];
        float l0 = s0 + LSs[t * 2], l1 = s1 + LSs[t * 2 + 1];
        float p00 = s0 * l0, p01 = s0 * l1, p10 = s1 * l0, p11 = s1 * l1;
        for (int o = 32; o; o >>= 1) {
            p00 += __shfl_down(p00, o); p01 += __shfl_down(p01, o);
            p10 += __shfl_down(p10, o); p11 += __shfl_down(p11, o);
        }
        if (t == 0) {
            float r0 = fmaxf(fabsf(p00) + fabsf(p01), 1e-12f);
            float r1 = fmaxf(fabsf(p10) + fabsf(p11), 1e-12f);
            float d0 = p00 / r0 - 1.0f, d1 = p11 / r1 - 1.0f;
            pens[g] = 0.5f * (d0 * d0 + d1 * d1);
        }
    }
    {
        int k = t & 63, p = t >> 6;
        const float* xg = x + (size_t)g * 4096 + k;
        float qk = 0.f;
#pragma unroll 4
        for (int nn = p * 16; nn < p * 16 + 16; ++nn)
            qk += cws[nn] * xg[(size_t)nn * 64];
        __syncthreads();              // all P4 reads of Ys long done; reuse as partials
        Ys[p * 64 + k] = qk;
    }
    __syncthreads();
    if (t < 64)
        Qh[(size_t)g * 64 + t] = 0.5f * (Ys[t] + Ys[64 + t] + Ys[128 + t] + Ys[192 + t]);
}

// ---------------------------------------------------------------------------
// Parallel CSR build over pos_edges (3 small kernels).
// ---------------------------------------------------------------------------
__global__ void k_cnt(const int* __restrict__ pd, int* __restrict__ icnt) {
    int e = blockIdx.x * 256 + threadIdx.x;
    atomicAdd(&icnt[pd[e]], 1);
}

__global__ void k_scan(const int* __restrict__ icnt, int* __restrict__ offs,
                       int* __restrict__ curs, float* __restrict__ dinv) {
    __shared__ int wsum[4];
    int t = threadIdx.x;
    int base = t * 16;
    int l0,l1,l2,l3,l4,l5,l6,l7,l8,l9,l10,l11,l12,l13,l14,l15;
    l0=icnt[base+0]; l1=icnt[base+1]; l2=icnt[base+2]; l3=icnt[base+3];
    l4=icnt[base+4]; l5=icnt[base+5]; l6=icnt[base+6]; l7=icnt[base+7];
    l8=icnt[base+8]; l9=icnt[base+9]; l10=icnt[base+10]; l11=icnt[base+11];
    l12=icnt[base+12]; l13=icnt[base+13]; l14=icnt[base+14]; l15=icnt[base+15];
    int s = l0+l1+l2+l3+l4+l5+l6+l7+l8+l9+l10+l11+l12+l13+l14+l15;
    int lane = t & 63, w = t >> 6;
    int v = s;
    for (int o = 1; o < 64; o <<= 1) { int u = __shfl_up(v, o); if (lane >= o) v += u; }
    if (lane == 63) wsum[w] = v;
    __syncthreads();
    int woff = 0;
    for (int i = 0; i < 4; ++i) if (i < w) woff += wsum[i];
    int run = woff + v - s;
#define SC(L, I) offs[base+(I)] = run; curs[base+(I)] = run; \
    dinv[base+(I)] = rsqrtf((float)(L) + 1.0f); run += L;
    SC(l0,0) SC(l1,1) SC(l2,2) SC(l3,3) SC(l4,4) SC(l5,5) SC(l6,6) SC(l7,7)
    SC(l8,8) SC(l9,9) SC(l10,10) SC(l11,11) SC(l12,12) SC(l13,13) SC(l14,14) SC(l15,15)
#undef SC
}

__global__ void k_place(const int* __restrict__ pe, const float* __restrict__ dinv,
                        int* __restrict__ curs, int* __restrict__ csr_src,
                        float* __restrict__ csr_nrm) {
    int e = blockIdx.x * 256 + threadIdx.x;
    int s = pe[e], d = pe[EP + e];
    int pos = atomicAdd(&curs[d], 1);
    csr_src[pos] = s;
    csr_nrm[pos] = dinv[s] * dinv[d];
}

// ---------------------------------------------------------------------------
// CSR gathers: out[g] = in[g]*dinv[g]^2 + sum_{edges->g} in[src]*nrm.
// ---------------------------------------------------------------------------
__global__ void k_gather128(const int* __restrict__ offs, const int* __restrict__ icnt,
                            const int* __restrict__ csr_src, const float* __restrict__ csr_nrm,
                            const float* __restrict__ dinv, const float* __restrict__ in,
                            float* __restrict__ out) {
    int g = blockIdx.x, d = threadIdx.x;  // 128 threads
    float dv = dinv[g];
    float acc = in[(size_t)g * 128 + d] * dv * dv;
    int o = offs[g], c = icnt[g];
    for (int j = 0; j < c; ++j)
        acc += in[(size_t)csr_src[o + j] * 128 + d] * csr_nrm[o + j];
    out[(size_t)g * 128 + d] = acc;
}

__global__ void k_gather256(const int* __restrict__ offs, const int* __restrict__ icnt,
                            const int* __restrict__ csr_src, const float* __restrict__ csr_nrm,
                            const float* __restrict__ dinv, const float* __restrict__ in,
                            float* __restrict__ out) {
    int g = blockIdx.x, d = threadIdx.x;  // 256 threads
    float dv = dinv[g];
    float acc = in[(size_t)g * 256 + d] * dv * dv;
    int o = offs[g], c = icnt[g];
    for (int j = 0; j < c; ++j)
        acc += in[(size_t)csr_src[o + j] * 256 + d] * csr_nrm[o + j];
    out[(size_t)g * 256 + d] = acc;
}

// ---------------------------------------------------------------------------
// Double-buffered tiled fp32 GEMM (unchanged): 64x64 tile, 256 threads,
// 4x4 microtile, BK=32, register-prefetch + 2x LDS buffers.
// Dual-output option: blockIdx.y >= gridDim.y/2 uses B1/bias1/C1 (shared A).
// ---------------------------------------------------------------------------
__global__ __launch_bounds__(256) void k_gemm(
    const float* __restrict__ A,
    const float* __restrict__ B0, const float* __restrict__ bias0, float* __restrict__ C0,
    const float* __restrict__ B1, const float* __restrict__ bias1, float* __restrict__ C1,
    int M, int K, int N, int dorelu)
{
    __shared__ __align__(16) float lds[2 * 4352];
    const float* B = B0; const float* bias = bias0; float* C = C0;
    int by = blockIdx.y;
    if (B1 != nullptr && by >= (int)(gridDim.y >> 1)) {
        B = B1; bias = bias1; C = C1; by -= (gridDim.y >> 1);
    }
    const int mb = blockIdx.x * 64, nbb = by * 64;
    const int t = threadIdx.x;
    const int tm4 = (t >> 4) * 4, tn4 = (t & 15) * 4;
    const int ma = t >> 2, ka = (t & 3) * 8;
    const int kb = t >> 3, nb8 = (t & 7) * 8;

    float4 pa0, pa1, pb0, pb1;
#define LOADT(K0) { \
    const float* Ap = &A[(size_t)(mb + ma) * K + (K0) + ka]; \
    pa0 = *(const float4*)Ap; pa1 = *(const float4*)(Ap + 4); \
    const float* Bp = &B[(size_t)((K0) + kb) * N + nbb + nb8]; \
    pb0 = *(const float4*)Bp; pb1 = *(const float4*)(Bp + 4); }
#define STORET(BUF) { \
    float* At_ = lds + (BUF) * 4352; \
    At_[(ka + 0) * 68 + ma] = pa0.x; At_[(ka + 1) * 68 + ma] = pa0.y; \
    At_[(ka + 2) * 68 + ma] = pa0.z; At_[(ka + 3) * 68 + ma] = pa0.w; \
    At_[(ka + 4) * 68 + ma] = pa1.x; At_[(ka + 5) * 68 + ma] = pa1.y; \
    At_[(ka + 6) * 68 + ma] = pa1.z; At_[(ka + 7) * 68 + ma] = pa1.w; \
    float* Bs_ = lds + (BUF) * 4352 + 2176; \
    *(float4*)&Bs_[kb * 68 + nb8] = pb0; *(float4*)&Bs_[kb * 68 + nb8 + 4] = pb1; }

    float4 ca0 = {0,0,0,0}, ca1 = {0,0,0,0}, ca2 = {0,0,0,0}, ca3 = {0,0,0,0};
    const int nk0 = K >> 5;
    LOADT(0)
    STORET(0)
    __syncthreads();
    for (int it = 0; it < nk0; ++it) {
        if (it + 1 < nk0) LOADT((it + 1) * 32)
        const float* At_ = lds + (it & 1) * 4352;
        const float* Bs_ = At_ + 2176;
#pragma unroll
        for (int k = 0; k < 32; ++k) {
            float4 av = *(const float4*)&At_[k * 68 + tm4];
            float4 bv = *(const float4*)&Bs_[k * 68 + tn4];
            ca0.x += av.x * bv.x; ca0.y += av.x * bv.y; ca0.z += av.x * bv.z; ca0.w += av.x * bv.w;
            ca1.x += av.y * bv.x; ca1.y += av.y * bv.y; ca1.z += av.y * bv.z; ca1.w += av.y * bv.w;
            ca2.x += av.z * bv.x; ca2.y += av.z * bv.y; ca2.z += av.z * bv.z; ca2.w += av.z * bv.w;
            ca3.x += av.w * bv.x; ca3.y += av.w * bv.y; ca3.z += av.w * bv.z; ca3.w += av.w * bv.w;
        }
        if (it + 1 < nk0) {
            STORET((it + 1) & 1)
            __syncthreads();
        }
    }
#undef LOADT
#undef STORET
    float4 bv4 = {0, 0, 0, 0};
    if (bias) bv4 = *(const float4*)&bias[nbb + tn4];
#define CST(I, CV) { \
    float4 v; v.x = CV.x + bv4.x; v.y = CV.y + bv4.y; v.z = CV.z + bv4.z; v.w = CV.w + bv4.w; \
    if (dorelu) { v.x = fmaxf(v.x, 0.f); v.y = fmaxf(v.y, 0.f); v.z = fmaxf(v.z, 0.f); v.w = fmaxf(v.w, 0.f); } \
    *(float4*)&C[(size_t)(mb + tm4 + (I)) * N + nbb + tn4] = v; }
    CST(0, ca0) CST(1, ca1) CST(2, ca2) CST(3, ca3)
#undef CST
}

// z = mu + eps*exp(min(ls,10)); zc = [emb, z]; per-graph KL partial.
// Also a[g] = dot(zc[g], w1b2), b[g] = dot(zc[g], w2b1) for the
// bilinear-form pred (folds the bias terms of fx.fy).
__global__ void k_fin_z(const float* __restrict__ mu_arr, const float* __restrict__ ls_arr,
                        const float* __restrict__ eps, const float* __restrict__ emb,
                        const float* __restrict__ w1b2, const float* __restrict__ w2b1,
                        float* __restrict__ zc, float* __restrict__ klp,
                        float* __restrict__ a_arr, float* __restrict__ b_arr) {
    __shared__ float smw[6];
    int g = blockIdx.x, d = threadIdx.x;  // 128 threads
    int idx = g * 128 + d;
    float mu = mu_arr[idx];
    float ls = fminf(ls_arr[idx], 10.0f);
    float e  = __expf(ls);
    float z = mu + eps[idx] * e;
    float em = emb[idx];
    zc[(size_t)g * 256 + d] = em;
    zc[(size_t)g * 256 + 128 + d] = z;
    float term = 1.0f + 2.0f * ls - mu * mu - e * e;
    float av = em * w1b2[d] + z * w1b2[128 + d];
    float bv = em * w2b1[d] + z * w2b1[128 + d];
    for (int o = 32; o; o >>= 1) {
        term += __shfl_down(term, o);
        av   += __shfl_down(av, o);
        bv   += __shfl_down(bv, o);
    }
    if ((d & 63) == 0) { int w = d >> 6; smw[w] = term; smw[2 + w] = av; smw[4 + w] = bv; }
    __syncthreads();
    if (d == 0) {
        klp[g]   = smw[0] + smw[1];
        a_arr[g] = smw[2] + smw[3];
        b_arr[g] = smw[4] + smw[5];
    }
}

// Edge predictions via bilinear form: sigmoid(dot(zc[s], U[d]) + a[s] +
// b[d] + c). 16 lanes per edge; per-block log partial (16 edges).
__global__ void k_pred(const float* __restrict__ ZC, const float* __restrict__ U,
                       const float* __restrict__ a_arr, const float* __restrict__ b_arr,
                       const float* __restrict__ cconst,
                       const int* __restrict__ pos, const int* __restrict__ neg,
                       float* __restrict__ out, float* __restrict__ predp) {
    __shared__ float smw[16];
    int t = threadIdx.x, sub = t >> 4, l = t & 15;
    int eg = blockIdx.x * 16 + sub;
    int isneg = eg >= EP;
    int e = eg - (isneg ? EP : 0);
    const int* eix = isneg ? neg : pos;
    int s = eix[e], d = eix[EP + e];
    const float4* Ar = (const float4*)(ZC + (size_t)s * 256);
    const float4* Br = (const float4*)(U + (size_t)d * 256);
    float dot = 0.f;
#pragma unroll
    for (int q = 0; q < 4; ++q) {
        float4 av = Ar[l + 16 * q], bv = Br[l + 16 * q];
        dot += av.x * bv.x + av.y * bv.y + av.z * bv.z + av.w * bv.w;
    }
    for (int o = 8; o; o >>= 1) dot += __shfl_down(dot, o);
    if (l == 0) {
        dot += a_arr[s] + b_arr[d] + cconst[0];
        float p = 1.0f / (1.0f + __expf(-dot));
        float term;
        if (isneg) { out[2 + EP + e] = p; term = __logf(1.0f - p + 1e-15f); }
        else       { out[2 + e] = p;      term = __logf(p + 1e-15f); }
        smw[sub] = term;
    }
    __syncthreads();
    if (t == 0) {
        float s16 = 0.f;
#pragma unroll
        for (int i = 0; i < 16; ++i) s16 += smw[i];
        predp[blockIdx.x] = s16;
    }
}

// Final scalar reductions (predp: 2048 pos + 2048 neg)
__global__ void k_final(const float* __restrict__ pens, const float* __restrict__ klp,
                        const float* __restrict__ predp, float* __restrict__ out) {
    __shared__ float sm[16];
    int t = threadIdx.x;
    float s_pen = 0.f, s_kl = 0.f, s_pos = 0.f, s_neg = 0.f;
    for (int i = t; i < 4096; i += 256) { s_pen += pens[i]; s_kl += klp[i]; }
    for (int i = t; i < 2048; i += 256) { s_pos += predp[i]; s_neg += predp[2048 + i]; }
    for (int o = 32; o; o >>= 1) {
        s_pen += __shfl_down(s_pen, o); s_kl += __shfl_down(s_kl, o);
        s_pos += __shfl_down(s_pos, o); s_neg += __shfl_down(s_neg, o);
    }
    int w = t >> 6;
    if ((t & 63) == 0) { sm[w] = s_pen; sm[4 + w] = s_kl; sm[8 + w] = s_pos; sm[12 + w] = s_neg; }
    __syncthreads();
    if (t == 0) {
        float pen = sm[0] + sm[1] + sm[2] + sm[3];
        float kls = sm[4] + sm[5] + sm[6] + sm[7];
        float pos = sm[8] + sm[9] + sm[10] + sm[11];
        float neg = sm[12] + sm[13] + sm[14] + sm[15];
        float rec = -(pos / 32768.0f) - (neg / 32768.0f);
        out[0] = rec - 0.5f * kls / (4096.0f * 4096.0f);
        out[1] = pen * (1.0f / 4096.0f);
    }
}

extern "C" void kernel_launch(void* const* d_in, const int* in_sizes, int n_in,
                              void* d_out, int out_size, void* d_ws, size_t ws_size,
                              hipStream_t stream) {
    const float* x   = (const float*)d_in[0];
    const int*   ei  = (const int*)d_in[1];
    const float* ew  = (const float*)d_in[2];
    const int*   pos = (const int*)d_in[3];
    const int*   neg = (const int*)d_in[4];
    const float* eps = (const float*)d_in[5];
    const float* Wg  = (const float*)d_in[6];
    const float* bg  = (const float*)d_in[7];
    const float* Wf1 = (const float*)d_in[8];
    const float* bf1 = (const float*)d_in[9];
    const float* Wf2 = (const float*)d_in[10];
    const float* bf2 = (const float*)d_in[11];
    const float* Wc1 = (const float*)d_in[12];
    const float* bc1 = (const float*)d_in[13];
    const float* Wmu = (const float*)d_in[14];
    const float* bmu = (const float*)d_in[15];
    const float* Wls = (const float*)d_in[16];
    const float* bls = (const float*)d_in[17];
    const float* emb = (const float*)d_in[18];
    const float* Wl1 = (const float*)d_in[19];
    const float* bl1 = (const float*)d_in[20];
    const float* Wl2 = (const float*)d_in[21];
    const float* bl2 = (const float*)d_in[22];
    float* out = (float*)d_out;
    float* ws  = (float*)d_ws;

    // Workspace layout (floats), footprint unchanged (~30.84 MB)
    float* g_embs  = ws + 0;         // 524288
    float* dinv    = ws + 524288;    // 4096
    int*   icnt_g  = (int*)(ws + 528384);  // 4096
    int*   off_g   = (int*)(ws + 532480);  // 4096
    int*   cur_g   = (int*)(ws + 536576);  // 4096
    int*   csr_src = (int*)(ws + 540672);  // 32768
    float* csr_nrm = ws + 573440;    // 32768
    float* Qh      = ws + 606208;    // 262144
    float* ga      = ws + 868352;    // 524288
    float* h       = ws + 1392640;   // 1048576
    float* ha      = ws + 2441216;   // 1048576
    float* mu_arr  = ws + 3489792;   // 524288
    float* ls_arr  = ws + 4014080;   // 524288
    float* zc      = ws + 4538368;   // 1048576
    float* Ubuf    = ws + 5586944;   // 1048576 (only 1/4 used now)
    float* MT      = ws + 6635520;   // 65536
    float* w1b2    = ws + 6701056;   // 256
    float* w2b1    = ws + 6701312;   // 256
    float* cconst  = ws + 6701568;   // 1
    float* pens    = ws + 7684096;   // 4096
    float* klp     = ws + 7688192;   // 4096
    float* predp   = ws + 7692288;   // 4096
    float* a_arr   = ws + 7696384;   // 4096
    float* b_arr   = ws + 7700480;   // 4096
    float* Wgf1    = ws + 7708672;   // 1024
    float* bcomb   = ws + 7709696;   // 16
    float* bg32    = ws + 7709712;   // 128
    // Y (262144 x 16 = 4,194,304 floats) overlaps h..zc exactly:
    // [1392640, 5586944). All of h/ha/mu/ls/zc are written only AFTER k_pg
    // has consumed Y (in-stream order), so this adds no workspace.
    float* Y       = ws + 1392640;

    // Prep (R7 form), MT+biases (parallel), Y precompute, per-graph stage
    k_prep<<<1, 256, 0, stream>>>(Wg, Wf1, bf1, bg, Wgf1, bcomb, bg32, icnt_g);
    k_mt<<<256, 256, 0, stream>>>(Wl1, Wl2, bl1, bl2, MT, w1b2, w2b1, cconst);
    k_y<<<1024, 256, 0, stream>>>(x, Wgf1, Y);
    k_pg<<<GG, 256, 0, stream>>>(Y, ei, ew, x, bcomb, Wf2, bf2, Qh, pens);
    // g_embs = Qh @ Wg + 32*bg
    k_gemm<<<dim3(64, 2), 256, 0, stream>>>(Qh, Wg, bg32, g_embs,
                                            nullptr, nullptr, nullptr, GG, 64, 128, 0);

    // Parallel CSR build over pos_edges
    k_cnt<<<EP / 256, 256, 0, stream>>>(pos + EP, icnt_g);
    k_scan<<<1, 256, 0, stream>>>(icnt_g, off_g, cur_g, dinv);
    k_place<<<EP / 256, 256, 0, stream>>>(pos, dinv, cur_g, csr_src, csr_nrm);

    // h = relu((A g_embs) @ Wc1 + bc1)
    k_gather128<<<GG, 128, 0, stream>>>(off_g, icnt_g, csr_src, csr_nrm, dinv, g_embs, ga);
    k_gemm<<<dim3(64, 4), 256, 0, stream>>>(ga, Wc1, bc1, h,
                                            nullptr, nullptr, nullptr, GG, 128, 256, 1);

    // mu/ls = (A h) @ {Wmu,Wls} + {bmu,bls}
    k_gather256<<<GG, 256, 0, stream>>>(off_g, icnt_g, csr_src, csr_nrm, dinv, h, ha);
    k_gemm<<<dim3(64, 4), 256, 0, stream>>>(ha, Wmu, bmu, mu_arr,
                                            Wls, bls, ls_arr, GG, 256, 128, 0);
    k_fin_z<<<GG, 128, 0, stream>>>(mu_arr, ls_arr, eps, emb, w1b2, w2b1,
                                    zc, klp, a_arr, b_arr);

    // U = zc @ MT  (single product replaces the dual gemm4)
    k_gemm<<<dim3(64, 4), 256, 0, stream>>>(zc, MT, nullptr, Ubuf,
                                            nullptr, nullptr, nullptr, GG, 256, 256, 0);

    // Edge predictions + scalars (16 edges/block)
    k_pred<<<(2 * EP) / 16, 256, 0, stream>>>(zc, Ubuf, a_arr, b_arr, cconst,
                                              pos, neg, out, predp);
    k_final<<<1, 256, 0, stream>>>(pens, klp, predp, out);
}